// Round 8
// baseline (218.043 us; speedup 1.0000x reference)
//
#include <hip/hip_runtime.h>

// VQ-VAE vector quantization, MI355X gfx950.
// B=16, C=64, H=W=64 -> N=65536 pixels; K=1024 codes, dim 64.
// NUMERICS (DO NOT CHANGE — r7 passed absmax 0.0 with exactly this):
//   nz/ne: numpy pairwise sum, 8-accumulator unroll, products rounded
//          separately (no fma contraction);
//   dot:   single ascending fp32 fma chain per (pixel,code);
//   d = fl( fl(nz - fl(2*dot)) + ne ); strict-< ascending-k tie-break.
//   ~135 pixels are decided by quantized ties.
//
// Perf history:
//   r7 161 | r8 185 | r9 137 | r12 242 | r13 137 | r14 1244 | r15 135
//   r16 hybrid LDS+SGPR argmin 133 µs (best) — argmin flat 133-138 across
//       6 structures; LDS b128 broadcast ~12cyc is the co-binding pipe.
//   r17 argmin KCHUNK=256: 138 (512 blocks = 2/CU, TLP loss). finalize
//       FB=128: REGRESSED — 512 blocks / 256 CU = still 4 waves/CU; the
//       predicted 8 waves never materialized. finalize is latency-bound.
// r18: argmin = r16 VERBATIM (133 µs). finalize restructured: block=256
//   handles 64 pixels, wave w does channels [16w,16w+16) of all 64 —
//   grid 1024 blocks = 4 blocks/CU = 16 waves/CU (4x TLP), threads 4x
//   shorter (~34 VMEM). Wave-level coalescing identical to validated
//   rounds (all lanes same c, consecutive hw). Phase 1: wave 0 chunk-
//   reduce (float4/int4) -> bi in LDS + indices out. Phase 2: all waves
//   gather emb segment (4x float4) + z/zq strided + partial SSE.
#define N_PIX   65536
#define CDIM    64
#define KCODES  1024
#define HWSZ    4096          // H*W
#define KCHUNK  128           // codes per argmin block
#define NCHUNK  8             // KCODES / KCHUNK
#define TPB     256
#define PXT     2             // pixels per thread; 128*256*2 == N_PIX exactly
#define GRIDX   (N_PIX / (TPB * PXT))   // 128
#define FPIX    64            // pixels per finalize block -> 1024 blocks

// workspace layout (float-element offsets) — r16 layout
#define OFF_CTR  0            // 1 u32: finalize done-counter
#define OFF_MIN  1024         // 65536*8 f32: per-chunk min score
#define OFF_IDX  525312       // 65536*8 i32: per-chunk argmin
#define OFF_LOSS 1049600      // 1 f32: SSE accumulator

// output layout (float-element offsets): z_q | indices | loss
#define OUT_IDX  (N_PIX * CDIM)         // 4194304
#define OUT_LOSS (OUT_IDX + N_PIX)      // 4259840

typedef __attribute__((ext_vector_type(16))) float f32x16;

// exact numpy pairwise ||.||^2 for pixel registers — EXACT r9-verified form.
__device__ __forceinline__ float np_nz(const float* zr) {
    float r0 = zr[0]*zr[0], r1 = zr[1]*zr[1], r2 = zr[2]*zr[2], r3 = zr[3]*zr[3];
    float r4 = zr[4]*zr[4], r5 = zr[5]*zr[5], r6 = zr[6]*zr[6], r7 = zr[7]*zr[7];
#pragma unroll
    for (int i = 8; i < CDIM; i += 8) {
        r0 = r0 + zr[i+0]*zr[i+0]; r1 = r1 + zr[i+1]*zr[i+1];
        r2 = r2 + zr[i+2]*zr[i+2]; r3 = r3 + zr[i+3]*zr[i+3];
        r4 = r4 + zr[i+4]*zr[i+4]; r5 = r5 + zr[i+5]*zr[i+5];
        r6 = r6 + zr[i+6]*zr[i+6]; r7 = r7 + zr[i+7]*zr[i+7];
    }
    return ((r0 + r1) + (r2 + r3)) + ((r4 + r5) + (r6 + r7));
}

// ---------------- Kernel A: split-K argmin, hybrid LDS+SGPR (r16 verbatim) --
// grid = (GRIDX, NCHUNK); block = TPB.
__global__ __launch_bounds__(TPB, 3) void vq_argmin(const float* __restrict__ z,
                                                    const float* __restrict__ emb,
                                                    float* __restrict__ cmin,
                                                    int* __restrict__ cidx,
                                                    float* __restrict__ ws) {
#pragma clang fp contract(off)
    __shared__ float se[KCHUNK * CDIM];   // 32 KB
    __shared__ float sn[KCHUNK];

    const int chunk = blockIdx.y;
    const int k0 = chunk * KCHUNK;

    if ((blockIdx.x | blockIdx.y) == 0 && threadIdx.x == 0) {
        ws[OFF_LOSS] = 0.0f;                       // stream-ordered before finalize
        ((unsigned*)ws)[OFF_CTR] = 0u;             // graph-replay / re-poison safe
    }

    // stage this chunk's embedding rows (coalesced float4)
    const float4* esrc = (const float4*)(emb + (size_t)k0 * CDIM);
    float4* edst = (float4*)se;
    for (int i = threadIdx.x; i < KCHUNK * CDIM / 4; i += TPB) edst[i] = esrc[i];
    __syncthreads();
    // fused prep: ||e_k||^2 from the bit-exact staged copy (validated r12-r16).
    // Known cost: 32-way bank conflict here, ~2M cycles (~3 µs). Accepted.
    if (threadIdx.x < KCHUNK) {
        const float* e = se + threadIdx.x * CDIM;
        float r0 = e[0]*e[0], r1 = e[1]*e[1], r2 = e[2]*e[2], r3 = e[3]*e[3];
        float r4 = e[4]*e[4], r5 = e[5]*e[5], r6 = e[6]*e[6], r7 = e[7]*e[7];
#pragma unroll
        for (int i = 8; i < CDIM; i += 8) {
            r0 = r0 + e[i+0]*e[i+0]; r1 = r1 + e[i+1]*e[i+1];
            r2 = r2 + e[i+2]*e[i+2]; r3 = r3 + e[i+3]*e[i+3];
            r4 = r4 + e[i+4]*e[i+4]; r5 = r5 + e[i+5]*e[i+5];
            r6 = r6 + e[i+6]*e[i+6]; r7 = r7 + e[i+7]*e[i+7];
        }
        sn[threadIdx.x] = ((r0 + r1) + (r2 + r3)) + ((r4 + r5) + (r6 + r7));
    }
    __syncthreads();

    // two pixels per thread, lane-coalesced; no tail (128*256*2 == N_PIX)
    const int p0 = blockIdx.x * (TPB * PXT) + threadIdx.x;
    const int p1 = p0 + TPB;

    float zr0[CDIM], zr1[CDIM];
    {
        const int b0  = p0 >> 12, hw0 = p0 & (HWSZ - 1);
        const int b1  = p1 >> 12, hw1 = p1 & (HWSZ - 1);
        const float* zp0 = z + ((size_t)(b0 * CDIM) << 12) + hw0;
        const float* zp1 = z + ((size_t)(b1 * CDIM) << 12) + hw1;
#pragma unroll
        for (int c = 0; c < CDIM; ++c) {
            zr0[c] = zp0[(size_t)c << 12];
            zr1[c] = zp1[(size_t)c << 12];
        }
    }
    const float nz0 = np_nz(zr0);
    const float nz1 = np_nz(zr1);

    float best0 = 3.4e38f, best1 = 3.4e38f;
    int   bi0   = k0,      bi1   = k0;

    for (int kk = 0; kk < KCHUNK; kk += 2) {
        // --- issue SGPR stream for code kk+1 (erow + 0x100..0x1c0) ---------
        const float* erow = emb + (size_t)(k0 + kk) * CDIM;
        f32x16 ec0, ec1, ec2, ec3;
        asm volatile(
            "s_load_dwordx16 %0, %4, 0x100\n\t"
            "s_load_dwordx16 %1, %4, 0x140\n\t"
            "s_load_dwordx16 %2, %4, 0x180\n\t"
            "s_load_dwordx16 %3, %4, 0x1c0"
            : "=s"(ec0), "=s"(ec1), "=s"(ec2), "=s"(ec3)
            : "s"(erow));

        // --- LDS phase: code kk for both pixels (r9's exact chains) --------
        const float4* e0 = (const float4*)(se + kk * CDIM);
        float a00 = 0.f, a01 = 0.f, a10 = 0.f, a11 = 0.f;
#pragma unroll
        for (int j = 0; j < 16; ++j) {
            float4 v0 = e0[j];                 // uniform addr -> LDS broadcast
            a00 = fmaf(zr0[4*j+0], v0.x, a00);
            a00 = fmaf(zr0[4*j+1], v0.y, a00);
            a00 = fmaf(zr0[4*j+2], v0.z, a00);
            a00 = fmaf(zr0[4*j+3], v0.w, a00);
            a10 = fmaf(zr1[4*j+0], v0.x, a10);
            a10 = fmaf(zr1[4*j+1], v0.y, a10);
            a10 = fmaf(zr1[4*j+2], v0.z, a10);
            a10 = fmaf(zr1[4*j+3], v0.w, a10);
        }

        // --- wait: pinned AFTER the LDS phase (produces a00,a10) and BEFORE
        //     the SGPR phase (consumes ec0..ec3 as this asm's outputs) -------
        asm volatile("s_waitcnt lgkmcnt(0)"
                     : "+s"(ec0), "+s"(ec1), "+s"(ec2), "+s"(ec3),
                       "+v"(a00), "+v"(a10));

        // --- SGPR phase: code kk+1 for both pixels (r15's exact chains) ----
#pragma unroll
        for (int j = 0; j < 16; ++j) {
            a01 = fmaf(zr0[j], ec0[j], a01);   // v_fma: VGPR,SGPR,VGPR
            a11 = fmaf(zr1[j], ec0[j], a11);
        }
#pragma unroll
        for (int j = 0; j < 16; ++j) {
            a01 = fmaf(zr0[16+j], ec1[j], a01);
            a11 = fmaf(zr1[16+j], ec1[j], a11);
        }
#pragma unroll
        for (int j = 0; j < 16; ++j) {
            a01 = fmaf(zr0[32+j], ec2[j], a01);
            a11 = fmaf(zr1[32+j], ec2[j], a11);
        }
#pragma unroll
        for (int j = 0; j < 16; ++j) {
            a01 = fmaf(zr0[48+j], ec3[j], a01);
            a11 = fmaf(zr1[48+j], ec3[j], a11);
        }

        // d and argmin — exact r9 expression shapes and update order
        float d00 = (nz0 - 2.0f * a00) + sn[kk];
        float d01 = (nz0 - 2.0f * a01) + sn[kk + 1];
        float d10 = (nz1 - 2.0f * a10) + sn[kk];
        float d11 = (nz1 - 2.0f * a11) + sn[kk + 1];
        if (d00 < best0) { best0 = d00; bi0 = k0 + kk; }
        if (d01 < best0) { best0 = d01; bi0 = k0 + kk + 1; }
        if (d10 < best1) { best1 = d10; bi1 = k0 + kk; }
        if (d11 < best1) { best1 = d11; bi1 = k0 + kk + 1; }
    }
    cmin[(p0 << 3) + chunk] = best0;
    cidx[(p0 << 3) + chunk] = bi0;
    cmin[(p1 << 3) + chunk] = best1;
    cidx[(p1 << 3) + chunk] = bi1;
}

// ---------------- Kernel B: reduce chunks, gather z_q, loss + emit ----------
// block = 256 threads handles FPIX=64 pixels; wave w owns channels
// [16w, 16w+16) of ALL 64 pixels. grid = 1024 blocks = 4 blocks/CU =
// 16 waves/CU. Per-wave access: all lanes same channel, consecutive hw ->
// identical coalescing to every validated round.
__global__ __launch_bounds__(TPB) void vq_finalize(const float* __restrict__ z,
                                                   const float* __restrict__ emb,
                                                   const float* __restrict__ cmin,
                                                   const int* __restrict__ cidx,
                                                   float* __restrict__ out,
                                                   float* __restrict__ ws) {
    const int lane = threadIdx.x & 63;
    const int wave = threadIdx.x >> 6;          // 0..3 -> channel group
    const int p    = blockIdx.x * FPIX + lane;  // this lane's pixel

    __shared__ int   sidx[FPIX];
    __shared__ float wsum[TPB / 64];

    // phase 1: wave 0 reduces the 8 chunk minima per pixel (ascending
    // strict < keeps earliest lowest-k minimum), publishes bi + indices out.
    if (wave == 0) {
        const float4* cmv = (const float4*)(cmin + ((size_t)p << 3));
        const int4*   civ = (const int4*)(cidx + ((size_t)p << 3));
        float4 cm0 = cmv[0], cm1 = cmv[1];
        int4   ci0 = civ[0], ci1 = civ[1];
        float best = cm0.x;  int bi = ci0.x;
        if (cm0.y < best) { best = cm0.y; bi = ci0.y; }
        if (cm0.z < best) { best = cm0.z; bi = ci0.z; }
        if (cm0.w < best) { best = cm0.w; bi = ci0.w; }
        if (cm1.x < best) { best = cm1.x; bi = ci1.x; }
        if (cm1.y < best) { best = cm1.y; bi = ci1.y; }
        if (cm1.z < best) { best = cm1.z; bi = ci1.z; }
        if (cm1.w < best) { best = cm1.w; bi = ci1.w; }
        sidx[lane] = bi;
        out[OUT_IDX + p] = (float)bi;       // indices output (fp32), coalesced
    }
    __syncthreads();

    const int bi = sidx[lane];
    const int b  = p >> 12;
    const int hw = p & (HWSZ - 1);
    const int c0 = wave << 4;                   // 16*wave
    const float* zp = z   + ((size_t)(b * CDIM + c0) << 12) + hw;
    float*       zq = out + ((size_t)(b * CDIM + c0) << 12) + hw;

    // emb segment for this pixel's winning row: 4 scattered float4 per lane
    float e[16];
    {
        const float4* ev = (const float4*)(emb + (size_t)bi * CDIM + c0);
#pragma unroll
        for (int j = 0; j < 4; ++j) {
            float4 v = ev[j];
            e[4*j+0] = v.x; e[4*j+1] = v.y; e[4*j+2] = v.z; e[4*j+3] = v.w;
        }
    }

    float ls = 0.0f;
#pragma unroll
    for (int j = 0; j < 16; ++j) {
        float zv = zp[(size_t)j << 12];         // coalesced strided load
        float d = e[j] - zv;                    // identical per-element math
        ls = fmaf(d, d, ls);
        zq[(size_t)j << 12] = e[j];             // coalesced strided store
    }

    // wave reduce -> block partials -> one atomic; last block emits loss
#pragma unroll
    for (int off = 32; off > 0; off >>= 1) ls += __shfl_down(ls, off);
    if (lane == 0) wsum[wave] = ls;
    __syncthreads();
    if (threadIdx.x == 0) {
        float s = (wsum[0] + wsum[1]) + (wsum[2] + wsum[3]);
        float* loss_acc = ws + OFF_LOSS;
        atomicAdd(loss_acc, s);
        __threadfence();                               // add visible before count
        unsigned* ctr = (unsigned*)ws + OFF_CTR;
        unsigned old = atomicAdd(ctr, 1u);
        if (old == (unsigned)(gridDim.x - 1)) {        // last block: all adds done
            __threadfence();
            float total = atomicAdd(loss_acc, 0.0f);   // coherent L2 read
            // vq_loss + beta*commitment = (1+0.25) * SSE / numel(z)
            out[OUT_LOSS] = total * (1.25f / (float)(N_PIX * CDIM));
        }
    }
}

extern "C" void kernel_launch(void* const* d_in, const int* in_sizes, int n_in,
                              void* d_out, int out_size, void* d_ws, size_t ws_size,
                              hipStream_t stream) {
    const float* z   = (const float*)d_in[0];
    const float* emb = (const float*)d_in[1];
    float* ws   = (float*)d_ws;
    float* out  = (float*)d_out;
    float* cmin = ws + OFF_MIN;
    int*   cidx = (int*)(ws + OFF_IDX);

    vq_argmin<<<dim3(GRIDX, NCHUNK), dim3(TPB), 0, stream>>>(z, emb, cmin, cidx, ws);
    vq_finalize<<<dim3(N_PIX / FPIX), dim3(TPB), 0, stream>>>(z, emb, cmin, cidx, out, ws);
}

// Round 9
// 200.847 us; speedup vs baseline: 1.0856x; 1.0856x over previous
//
#include <hip/hip_runtime.h>

// VQ-VAE vector quantization, MI355X gfx950.
// B=16, C=64, H=W=64 -> N=65536 pixels; K=1024 codes, dim 64.
// NUMERICS (DO NOT CHANGE — r7 passed absmax 0.0 with exactly this):
//   nz/ne: numpy pairwise sum, 8-accumulator unroll, products rounded
//          separately (no fma contraction);
//   dot:   single ascending fp32 fma chain per (pixel,code);
//   d = fl( fl(nz - fl(2*dot)) + ne ); strict-< ascending-k tie-break.
//   ~135 pixels are decided by quantized ties.
//
// Perf history:
//   r7 161 | r8 185 | r9 137 | r12 242 | r13 137 | r14 1244 | r15 135
//   r16 hybrid LDS+SGPR argmin 133, total 196 (BEST) — model: LDS pipe
//       1536 cyc/pair/CU vs VALU 1024/SIMD -> LDS-bound, VALUBusy 0.67-0.75.
//   r17 finalize FB=128: regressed (512 blocks = still 4 waves/CU).
//   r18 finalize wave-split 16 waves/CU: regressed again (total 218).
//       Finalize experiments closed; revert to r16 finalize.
// r19: argmin pipe rebalance — even code ch0-31 via LDS (8 b128/pair),
//   ch32-63 via a SECOND SMEM batch reusing freed SGPRs mid-pair
//   (ec0/ec1 die after odd ch0-31; eh0/eh1 issue is data-dep on a01 so
//   it cannot hoist past the frees; peak stays 64 SGPR buffer).
//   All dot chains remain single ascending fp32 fma chains (bit-exact).
//   LDS demand/pair/CU: 1536 -> 768 < VALU 1024 -> VALU-bound.
//   Staging: even-rows ch0-31 only (8.5 KB LDS); sn from global float4
//   (r17-validated bits, kills the 2M-cycle sn bank-conflict block).
#define N_PIX   65536
#define CDIM    64
#define KCODES  1024
#define HWSZ    4096          // H*W
#define KCHUNK  128           // codes per argmin block
#define NCHUNK  8             // KCODES / KCHUNK
#define TPB     256
#define PXT     2             // pixels per thread; 128*256*2 == N_PIX exactly
#define GRIDX   (N_PIX / (TPB * PXT))   // 128

// workspace layout (float-element offsets) — r16 layout
#define OFF_CTR  0            // 1 u32: finalize done-counter
#define OFF_MIN  1024         // 65536*8 f32: per-chunk min score
#define OFF_IDX  525312       // 65536*8 i32: per-chunk argmin
#define OFF_LOSS 1049600      // 1 f32: SSE accumulator

// output layout (float-element offsets): z_q | indices | loss
#define OUT_IDX  (N_PIX * CDIM)         // 4194304
#define OUT_LOSS (OUT_IDX + N_PIX)      // 4259840

typedef __attribute__((ext_vector_type(16))) float f32x16;

// exact numpy pairwise ||.||^2 for pixel registers — EXACT r9-verified form.
__device__ __forceinline__ float np_nz(const float* zr) {
    float r0 = zr[0]*zr[0], r1 = zr[1]*zr[1], r2 = zr[2]*zr[2], r3 = zr[3]*zr[3];
    float r4 = zr[4]*zr[4], r5 = zr[5]*zr[5], r6 = zr[6]*zr[6], r7 = zr[7]*zr[7];
#pragma unroll
    for (int i = 8; i < CDIM; i += 8) {
        r0 = r0 + zr[i+0]*zr[i+0]; r1 = r1 + zr[i+1]*zr[i+1];
        r2 = r2 + zr[i+2]*zr[i+2]; r3 = r3 + zr[i+3]*zr[i+3];
        r4 = r4 + zr[i+4]*zr[i+4]; r5 = r5 + zr[i+5]*zr[i+5];
        r6 = r6 + zr[i+6]*zr[i+6]; r7 = r7 + zr[i+7]*zr[i+7];
    }
    return ((r0 + r1) + (r2 + r3)) + ((r4 + r5) + (r6 + r7));
}

// ---------------- Kernel A: split-K argmin, 3-phase pair loop ---------------
// grid = (GRIDX, NCHUNK); block = TPB.
__global__ __launch_bounds__(TPB, 3) void vq_argmin(const float* __restrict__ z,
                                                    const float* __restrict__ emb,
                                                    float* __restrict__ cmin,
                                                    int* __restrict__ cidx,
                                                    float* __restrict__ ws) {
#pragma clang fp contract(off)
    __shared__ float se[(KCHUNK / 2) * 32];   // 8 KB: EVEN rows, channels 0..31
    __shared__ float sn[KCHUNK];

    const int chunk = blockIdx.y;
    const int k0 = chunk * KCHUNK;

    if ((blockIdx.x | blockIdx.y) == 0 && threadIdx.x == 0) {
        ws[OFF_LOSS] = 0.0f;                       // stream-ordered before finalize
        ((unsigned*)ws)[OFF_CTR] = 0u;             // graph-replay / re-poison safe
    }

    // stage EVEN rows' channels 0..31: se[r][c] = emb[k0+2r][c], c<32
    {
        const int nf4 = (KCHUNK / 2) * 8;          // 512 float4
        for (int i = threadIdx.x; i < nf4; i += TPB) {
            const int r  = i >> 3;                 // 8 float4 per row
            const int c4 = i & 7;
            ((float4*)se)[i] =
                *((const float4*)(emb + (size_t)(k0 + 2 * r) * CDIM) + c4);
        }
    }
    // sn: ||e_k||^2 from GLOBAL emb, float4 loads, r7-identical arithmetic —
    // r17-validated bits (absmax 0.0), no LDS bank conflicts.
    if (threadIdx.x < KCHUNK) {
        const int k = threadIdx.x;
        const float4* ep = (const float4*)(emb + (size_t)(k0 + k) * CDIM);
        float e[CDIM];
#pragma unroll
        for (int j = 0; j < 16; ++j) {
            float4 v = ep[j];
            e[4*j+0] = v.x; e[4*j+1] = v.y; e[4*j+2] = v.z; e[4*j+3] = v.w;
        }
        float r0 = e[0]*e[0], r1 = e[1]*e[1], r2 = e[2]*e[2], r3 = e[3]*e[3];
        float r4 = e[4]*e[4], r5 = e[5]*e[5], r6 = e[6]*e[6], r7 = e[7]*e[7];
#pragma unroll
        for (int i = 8; i < CDIM; i += 8) {
            r0 = r0 + e[i+0]*e[i+0]; r1 = r1 + e[i+1]*e[i+1];
            r2 = r2 + e[i+2]*e[i+2]; r3 = r3 + e[i+3]*e[i+3];
            r4 = r4 + e[i+4]*e[i+4]; r5 = r5 + e[i+5]*e[i+5];
            r6 = r6 + e[i+6]*e[i+6]; r7 = r7 + e[i+7]*e[i+7];
        }
        sn[k] = ((r0 + r1) + (r2 + r3)) + ((r4 + r5) + (r6 + r7));
    }
    __syncthreads();

    // two pixels per thread, lane-coalesced; no tail (128*256*2 == N_PIX)
    const int p0 = blockIdx.x * (TPB * PXT) + threadIdx.x;
    const int p1 = p0 + TPB;

    float zr0[CDIM], zr1[CDIM];
    {
        const int b0  = p0 >> 12, hw0 = p0 & (HWSZ - 1);
        const int b1  = p1 >> 12, hw1 = p1 & (HWSZ - 1);
        const float* zp0 = z + ((size_t)(b0 * CDIM) << 12) + hw0;
        const float* zp1 = z + ((size_t)(b1 * CDIM) << 12) + hw1;
#pragma unroll
        for (int c = 0; c < CDIM; ++c) {
            zr0[c] = zp0[(size_t)c << 12];
            zr1[c] = zp1[(size_t)c << 12];
        }
    }
    const float nz0 = np_nz(zr0);
    const float nz1 = np_nz(zr1);

    float best0 = 3.4e38f, best1 = 3.4e38f;
    int   bi0   = k0,      bi1   = k0;

    for (int kk = 0; kk < KCHUNK; kk += 2) {
        const float* erow = emb + (size_t)(k0 + kk) * CDIM;

        // --- issue SMEM stream for ODD code kk+1 (full row, 0x100..0x1c0) --
        f32x16 ec0, ec1, ec2, ec3;
        asm volatile(
            "s_load_dwordx16 %0, %4, 0x100\n\t"
            "s_load_dwordx16 %1, %4, 0x140\n\t"
            "s_load_dwordx16 %2, %4, 0x180\n\t"
            "s_load_dwordx16 %3, %4, 0x1c0"
            : "=s"(ec0), "=s"(ec1), "=s"(ec2), "=s"(ec3)
            : "s"(erow));

        // --- even-lo: code kk ch0..31 from LDS broadcast (8 b128) ----------
        const float4* e0 = (const float4*)(se + (kk >> 1) * 32);
        float a00 = 0.f, a01 = 0.f, a10 = 0.f, a11 = 0.f;
#pragma unroll
        for (int j = 0; j < 8; ++j) {
            float4 v0 = e0[j];                 // uniform addr -> LDS broadcast
            a00 = fmaf(zr0[4*j+0], v0.x, a00);
            a00 = fmaf(zr0[4*j+1], v0.y, a00);
            a00 = fmaf(zr0[4*j+2], v0.z, a00);
            a00 = fmaf(zr0[4*j+3], v0.w, a00);
            a10 = fmaf(zr1[4*j+0], v0.x, a10);
            a10 = fmaf(zr1[4*j+1], v0.y, a10);
            a10 = fmaf(zr1[4*j+2], v0.z, a10);
            a10 = fmaf(zr1[4*j+3], v0.w, a10);
        }

        // --- wait#1: after even-lo (produces a00,a10), before odd use ------
        asm volatile("s_waitcnt lgkmcnt(0)"
                     : "+s"(ec0), "+s"(ec1), "+s"(ec2), "+s"(ec3),
                       "+v"(a00), "+v"(a10));

        // --- odd part 1: code kk+1 ch0..31 (frees ec0, ec1) ----------------
#pragma unroll
        for (int j = 0; j < 16; ++j) {
            a01 = fmaf(zr0[j], ec0[j], a01);   // v_fma: VGPR,SGPR,VGPR
            a11 = fmaf(zr1[j], ec0[j], a11);
        }
#pragma unroll
        for (int j = 0; j < 16; ++j) {
            a01 = fmaf(zr0[16+j], ec1[j], a01);
            a11 = fmaf(zr1[16+j], ec1[j], a11);
        }

        // --- issue even-hi SMEM batch (ch32..63 of code kk, 0x80/0xc0).
        //     "v"(a01) input makes this follow odd part 1, so ec0/ec1 are
        //     dead here and SGPR peak stays at the 64-reg buffer. ----------
        f32x16 eh0, eh1;
        asm volatile(
            "s_load_dwordx16 %0, %2, 0x80\n\t"
            "s_load_dwordx16 %1, %2, 0xc0"
            : "=s"(eh0), "=s"(eh1)
            : "s"(erow), "v"(a01));

        // --- odd part 2: code kk+1 ch32..63 (covers even-hi latency) -------
#pragma unroll
        for (int j = 0; j < 16; ++j) {
            a01 = fmaf(zr0[32+j], ec2[j], a01);
            a11 = fmaf(zr1[32+j], ec2[j], a11);
        }
#pragma unroll
        for (int j = 0; j < 16; ++j) {
            a01 = fmaf(zr0[48+j], ec3[j], a01);
            a11 = fmaf(zr1[48+j], ec3[j], a11);
        }

        // --- wait#2: after odd part 2 (produces a01,a11), before even-hi ---
        asm volatile("s_waitcnt lgkmcnt(0)"
                     : "+s"(eh0), "+s"(eh1), "+v"(a01), "+v"(a11));

        // --- even-hi: code kk ch32..63 — continues a00/a10 ascending -------
#pragma unroll
        for (int j = 0; j < 16; ++j) {
            a00 = fmaf(zr0[32+j], eh0[j], a00);
            a10 = fmaf(zr1[32+j], eh0[j], a10);
        }
#pragma unroll
        for (int j = 0; j < 16; ++j) {
            a00 = fmaf(zr0[48+j], eh1[j], a00);
            a10 = fmaf(zr1[48+j], eh1[j], a10);
        }

        // d and argmin — exact r9 expression shapes and update order
        float d00 = (nz0 - 2.0f * a00) + sn[kk];
        float d01 = (nz0 - 2.0f * a01) + sn[kk + 1];
        float d10 = (nz1 - 2.0f * a10) + sn[kk];
        float d11 = (nz1 - 2.0f * a11) + sn[kk + 1];
        if (d00 < best0) { best0 = d00; bi0 = k0 + kk; }
        if (d01 < best0) { best0 = d01; bi0 = k0 + kk + 1; }
        if (d10 < best1) { best1 = d10; bi1 = k0 + kk; }
        if (d11 < best1) { best1 = d11; bi1 = k0 + kk + 1; }
    }
    cmin[(p0 << 3) + chunk] = best0;
    cidx[(p0 << 3) + chunk] = bi0;
    cmin[(p1 << 3) + chunk] = best1;
    cidx[(p1 << 3) + chunk] = bi1;
}

// ---------------- Kernel B: reduce chunks, gather z_q, loss + emit ----------
// r16-verbatim (best measured finalize; r17/r18 restructures both regressed).
__global__ __launch_bounds__(TPB) void vq_finalize(const float* __restrict__ z,
                                                   const float* __restrict__ emb,
                                                   const float* __restrict__ cmin,
                                                   const int* __restrict__ cidx,
                                                   float* __restrict__ out,
                                                   float* __restrict__ ws) {
    const int p = blockIdx.x * TPB + threadIdx.x;

    // ascending-chunk strict < keeps the earliest (lowest-k) minimum
    float best = cmin[p << 3];
    int   bi   = cidx[p << 3];
#pragma unroll
    for (int ch = 1; ch < NCHUNK; ++ch) {
        float m = cmin[(p << 3) + ch];
        if (m < best) { best = m; bi = cidx[(p << 3) + ch]; }
    }

    out[OUT_IDX + p] = (float)bi;       // indices output (fp32)

    const float* ev = emb + bi * CDIM;
    const int b  = p >> 12;
    const int hw = p & (HWSZ - 1);
    const float* zp = z + ((size_t)(b * CDIM) << 12) + hw;
    float* zq = out + ((size_t)(b * CDIM) << 12) + hw;

    float ls = 0.0f;
#pragma unroll
    for (int c = 0; c < CDIM; ++c) {
        float e = ev[c];                    // gather: rows hit L1/L2 (256KB table)
        float zv = zp[(size_t)c << 12];
        float d = e - zv;
        ls = fmaf(d, d, ls);
        zq[(size_t)c << 12] = e;            // fp32 z_q, coalesced strided store
    }

    // block reduction -> one atomic per block; last block scales + emits loss
#pragma unroll
    for (int off = 32; off > 0; off >>= 1) ls += __shfl_down(ls, off);
    __shared__ float wsum[TPB / 64];
    if ((threadIdx.x & 63) == 0) wsum[threadIdx.x >> 6] = ls;
    __syncthreads();
    if (threadIdx.x == 0) {
        float s = wsum[0] + wsum[1] + wsum[2] + wsum[3];
        float* loss_acc = ws + OFF_LOSS;
        atomicAdd(loss_acc, s);
        __threadfence();                               // add visible before count
        unsigned* ctr = (unsigned*)ws + OFF_CTR;
        unsigned old = atomicAdd(ctr, 1u);
        if (old == (unsigned)(gridDim.x - 1)) {        // last block: all adds done
            __threadfence();
            float total = atomicAdd(loss_acc, 0.0f);   // coherent L2 read
            // vq_loss + beta*commitment = (1+0.25) * SSE / numel(z)
            out[OUT_LOSS] = total * (1.25f / (float)(N_PIX * CDIM));
        }
    }
}

extern "C" void kernel_launch(void* const* d_in, const int* in_sizes, int n_in,
                              void* d_out, int out_size, void* d_ws, size_t ws_size,
                              hipStream_t stream) {
    const float* z   = (const float*)d_in[0];
    const float* emb = (const float*)d_in[1];
    float* ws   = (float*)d_ws;
    float* out  = (float*)d_out;
    float* cmin = ws + OFF_MIN;
    int*   cidx = (int*)(ws + OFF_IDX);

    vq_argmin<<<dim3(GRIDX, NCHUNK), dim3(TPB), 0, stream>>>(z, emb, cmin, cidx, ws);
    vq_finalize<<<dim3(N_PIX / TPB), dim3(TPB), 0, stream>>>(z, emb, cmin, cidx, out, ws);
}